// Round 10
// baseline (171.856 us; speedup 1.0000x reference)
//
#include <hip/hip_runtime.h>
#include <math.h>

#define H_FULL 2160
#define W_FULL 3840
#define H_D    1080
#define W_D    1920
#define KLEN   17
#define INV_K2 (1.0f/289.0f)

typedef float f32x4 __attribute__((ext_vector_type(4)));

#if __has_builtin(__builtin_amdgcn_logf)
#define FAST_LOG2(x) __builtin_amdgcn_logf(x)
#else
#define FAST_LOG2(x) log2f(x)
#endif
#if __has_builtin(__builtin_amdgcn_exp2f)
#define FAST_EXP2(x) __builtin_amdgcn_exp2f(x)
#else
#define FAST_EXP2(x) exp2f(x)
#endif
#if __has_builtin(__builtin_amdgcn_rcpf)
#define FAST_RCP(x) __builtin_amdgcn_rcpf(x)
#else
#define FAST_RCP(x) (1.0f/(x))
#endif

static __device__ __forceinline__ int refl(int i, int n) {
    if (i < 0) i = -i;
    else if (i >= n) i = 2*n - 2 - i;
    return i;
}
static __device__ __forceinline__ float lum(float r, float g, float b) {
    return 0.2126f*r + 0.7152f*g + 0.0722f*b;
}
static __device__ __forceinline__ float lg(float y) {
    return FAST_LOG2(fmaxf(y, 1e-6f));
}
static __device__ __forceinline__ void nt_store4(float* p, float a, float b,
                                                 float c, float d) {
    f32x4 v; v.x = a; v.y = b; v.z = c; v.w = d;
    __builtin_nontemporal_store(v, (f32x4*)p);
}

// K1: luma + log2 + exact 2x2-average downsample. 2 outputs/thread, float4 loads.
__global__ __launch_bounds__(256) void k_down(const float* __restrict__ x,
                                              float* __restrict__ I) {
    int t = blockIdx.x * 256 + threadIdx.x;     // 0 .. 1,036,799
    int p = t * 2;
    int i = p / W_D;
    int j = p - i * W_D;                        // even
    const float4* r0 = (const float4*)(x + ((size_t)(2*i)   * W_FULL + 2*j) * 3);
    const float4* r1 = (const float4*)(x + ((size_t)(2*i+1) * W_FULL + 2*j) * 3);
    float4 a0 = r0[0], a1 = r0[1], a2 = r0[2];
    float4 b0 = r1[0], b1 = r1[1], b2 = r1[2];
    float y00 = lum(a0.x,a0.y,a0.z), y01 = lum(a0.w,a1.x,a1.y);
    float y02 = lum(a1.z,a1.w,a2.x), y03 = lum(a2.y,a2.z,a2.w);
    float y10 = lum(b0.x,b0.y,b0.z), y11 = lum(b0.w,b1.x,b1.y);
    float y12 = lum(b1.z,b1.w,b2.x), y13 = lum(b2.y,b2.z,b2.w);
    float o0 = 0.25f * (lg(y00)+lg(y01)+lg(y10)+lg(y11));
    float o1 = 0.25f * (lg(y02)+lg(y03)+lg(y12)+lg(y13));
    *(float2*)(I + (size_t)i * W_D + j) = make_float2(o0, o1);
}

// K2: guided filter (champion stages 1-5, R1-verified), writes base plane.
__global__ __launch_bounds__(512, 6) void k_filter(const float* __restrict__ I,
                                                   float* __restrict__ base) {
    __shared__ char lds[52088];
    float*  sIc   = (float*) (lds);             // 34x35 f   (4,760B)
    float*  sIf   = (float*) (lds + 4760);      // 66x67 f   (17,688B)
    float2* ab    = (float2*)(lds + 4760);      // 50x51 f2  (20,400B) (over sIf)
    float2* hI    = (float2*)(lds + 25160);     // 66x51 f2  (26,928B)
    float2* hab   = (float2*)(lds + 25160);     // 50x35 f2  (14,000B) (over hI)
    float*  baseL = (float*) (lds + 39160);     // 34x35 f   (4,760B)

    int tx0 = blockIdx.x * 32;
    int ty0 = blockIdx.y * 32;
    int tid = threadIdx.x;

    // stage 1: load 66x66 I halo (reflect), pitch 67
    for (int e = tid; e < 66 * 66; e += 512) {
        int r = e / 66, c = e - r * 66;
        sIf[r * 67 + c] =
            I[(size_t)refl(ty0 - 17 + r, H_D) * W_D + refl(tx0 - 17 + c, W_D)];
    }
    __syncthreads();

    // stage 2: horizontal 17-sums of (I, I*I): 66 rows x 50 cols
    if (tid < 330) {
        int r = tid / 5, run = tid - (tid / 5) * 5;
        int c0 = run * 10;
        const float* p = &sIf[r * 67 + c0];
        float s1 = 0.f, s2 = 0.f;
        #pragma unroll
        for (int k = 0; k < KLEN; ++k) { float v = p[k]; s1 += v; s2 += v * v; }
        float2* o = &hI[r * 51 + c0];
        o[0] = make_float2(s1, s2);
        #pragma unroll
        for (int m = 1; m < 10; ++m) {
            float vo = p[m - 1], vi = p[m + 16];
            s1 += vi - vo;
            s2 += vi * vi - vo * vo;
            o[m] = make_float2(s1, s2);
        }
    }
    for (int e = tid; e < 34 * 34; e += 512) {
        int r = e / 34, c = e - r * 34;
        sIc[r * 35 + c] = sIf[(r + 16) * 67 + (c + 16)];
    }
    __syncthreads();

    // stage 3: vertical 17-sums -> (a,b) on 50x50
    if (tid < 250) {
        int c = tid % 50, run = tid / 50;
        int r0 = run * 10;
        const float2* p = &hI[r0 * 51 + c];
        float s1 = 0.f, s2 = 0.f;
        #pragma unroll
        for (int k = 0; k < KLEN; ++k) { float2 v = p[k * 51]; s1 += v.x; s2 += v.y; }
        float2* o = &ab[r0 * 51 + c];
        #pragma unroll
        for (int m = 0; m < 10; ++m) {
            if (m) {
                float2 vi = p[(m + 16) * 51], vo = p[(m - 1) * 51];
                s1 += vi.x - vo.x;
                s2 += vi.y - vo.y;
            }
            float mI  = s1 * INV_K2;
            float mII = s2 * INV_K2;
            float var = mII - mI * mI;
            float av  = var / (var + 1e-3f);
            o[m * 51] = make_float2(av, mI - av * mI);
        }
    }
    __syncthreads();

    // stage 4: horizontal 17-sums of (a,b): 50 rows x 34 cols
    if (tid < 200) {
        int r = tid % 50, run = tid / 50;
        int c0  = (run < 2) ? run * 9 : 18 + (run - 2) * 8;
        int len = (run < 2) ? 9 : 8;
        const float2* p = &ab[r * 51 + c0];
        float sa = 0.f, sb = 0.f;
        #pragma unroll
        for (int k = 0; k < KLEN; ++k) { float2 v = p[k]; sa += v.x; sb += v.y; }
        float2* o = &hab[r * 35 + c0];
        o[0] = make_float2(sa, sb);
        #pragma unroll
        for (int m = 1; m < 9; ++m) {
            if (m < len) {
                float2 vi = p[m + 16], vo = p[m - 1];
                sa += vi.x - vo.x;
                sb += vi.y - vo.y;
                o[m] = make_float2(sa, sb);
            }
        }
    }
    __syncthreads();

    // stage 5: vertical 17-sums -> baseL 34x34; combine with sIc
    if (tid < 136) {
        int cc = tid % 34, run = tid / 34;
        int r0  = (run < 2) ? run * 9 : 18 + (run - 2) * 8;
        int len = (run < 2) ? 9 : 8;
        const float2* p = &hab[r0 * 35 + cc];
        float sa = 0.f, sb = 0.f;
        #pragma unroll
        for (int k = 0; k < KLEN; ++k) { float2 v = p[k * 35]; sa += v.x; sb += v.y; }
        #pragma unroll
        for (int m = 0; m < 9; ++m) {
            if (m < len) {
                if (m) {
                    float2 vi = p[(m + 16) * 35], vo = p[(m - 1) * 35];
                    sa += vi.x - vo.x;
                    sb += vi.y - vo.y;
                }
                int br = r0 + m;
                baseL[br * 35 + cc] =
                    (sa * INV_K2) * sIc[br * 35 + cc] + sb * INV_K2;
            }
        }
    }
    __syncthreads();

    // write the core 32x32 (baseL rows/cols 1..32) to the global base plane
    for (int e = tid; e < 32 * 32; e += 512) {
        int r = e >> 5, c = e & 31;
        int gr = ty0 + r;
        if (gr < H_D) base[(size_t)gr * W_D + (tx0 + c)] = baseL[(r + 1) * 35 + (c + 1)];
    }
}

// K3: deep-ILP streaming tone map. 16 px/thread: 12 independent float4 loads
// + 12 dense NT stores per thread (4x the in-flight bytes of the 4-px version)
// to test/break the MLP-limited ~3.3 TB/s mixed-stream wall. 2025 blocks.
__global__ __launch_bounds__(256) void k_tm16(const float* __restrict__ x,
                                              const float* __restrict__ base,
                                              float* __restrict__ out) {
    int t = blockIdx.x * 256 + threadIdx.x;     // 0 .. 518,399
    int oy = t / 240;                            // output row
    int g  = t - oy * 240;                       // 16-px group in row
    int j0 = g * 16;

    int y0g = (oy - 1) >> 1;
    int y0 = max(y0g, 0);
    int y1 = min(y0g + 1, H_D - 1);
    float wy = (oy & 1) ? 0.25f : 0.75f;
    const float* b0 = base + (size_t)y0 * W_D;
    const float* b1 = base + (size_t)y1 * W_D;

    // 12 independent x loads issued together (16px * 3ch = 48 floats)
    size_t off = ((size_t)oy * W_FULL + j0) * 3;
    const float4* px = (const float4*)(x + off);
    float4 q[12];
    #pragma unroll
    for (int i = 0; i < 12; ++i) q[i] = px[i];

    // base bilinear for 16 px: 4 subgroups of 4 (same math as verified k_tm,
    // with k2 = g*8 + 2s)
    float Yb[16];
    #pragma unroll
    for (int s = 0; s < 4; ++s) {
        int k2 = g * 8 + 2 * s;
        int c0 = max(k2 - 1, 0);
        int c3 = min(k2 + 2, W_D - 1);
        float u0 = b0[c0],     w0 = b1[c0];
        float u1 = b0[k2],     w1 = b1[k2];
        float u2 = b0[k2 + 1], w2 = b1[k2 + 1];
        float u3 = b0[c3],     w3 = b1[c3];
        float v0 = u0 + (w0 - u0) * wy;
        float v1 = u1 + (w1 - u1) * wy;
        float v2 = u2 + (w2 - u2) * wy;
        float v3 = u3 + (w3 - u3) * wy;
        Yb[4*s+0] = v0 + (v1 - v0) * 0.75f;
        Yb[4*s+1] = v1 + (v2 - v1) * 0.25f;
        Yb[4*s+2] = v1 + (v2 - v1) * 0.75f;
        Yb[4*s+3] = v2 + (v3 - v2) * 0.25f;
    }

    float f[48];
    #pragma unroll
    for (int i = 0; i < 12; ++i) {
        f[4*i] = q[i].x; f[4*i+1] = q[i].y; f[4*i+2] = q[i].z; f[4*i+3] = q[i].w;
    }
    float res[48];
    #pragma unroll
    for (int k = 0; k < 16; ++k) {
        float rr = f[3*k], gg = f[3*k+1], bb = f[3*k+2];
        float Y = lum(rr, gg, bb);
        float sc = fmaxf(Y, 1e-6f) * FAST_EXP2(-0.3f * Yb[k]) * FAST_RCP(Y + 1e-4f);
        res[3*k]   = fminf(fmaxf(rr * sc, 0.f), 1.f);
        res[3*k+1] = fminf(fmaxf(gg * sc, 0.f), 1.f);
        res[3*k+2] = fminf(fmaxf(bb * sc, 0.f), 1.f);
    }
    float* po = out + off;
    #pragma unroll
    for (int i = 0; i < 12; ++i)
        nt_store4(po + 4*i, res[4*i], res[4*i+1], res[4*i+2], res[4*i+3]);
}

extern "C" void kernel_launch(void* const* d_in, const int* in_sizes, int n_in,
                              void* d_out, int out_size, void* d_ws, size_t ws_size,
                              hipStream_t stream) {
    (void)in_sizes; (void)n_in; (void)out_size; (void)ws_size;
    const float* x = (const float*)d_in[0];
    float* out = (float*)d_out;
    float* I = (float*)d_ws;                         // 8.3 MB
    size_t plane = (size_t)H_D * W_D;
    float* base = I + plane;                         // 8.3 MB (ws >= 16B/px proven R6)

    k_down  <<<dim3(4050, 1, 1), dim3(256, 1, 1), 0, stream>>>(x, I);
    k_filter<<<dim3(60, 34, 1),  dim3(512, 1, 1), 0, stream>>>(I, base);
    k_tm16  <<<dim3(2025, 1, 1), dim3(256, 1, 1), 0, stream>>>(x, base, out);
}

// Round 11
// 67.211 us; speedup vs baseline: 2.5570x; 2.5570x over previous
//
#include <hip/hip_runtime.h>
#include <math.h>

#define H_FULL 2160
#define W_FULL 3840
#define H_D    1080
#define W_D    1920
#define KLEN   17
#define INV_K2 (1.0f/289.0f)

typedef float f32x4 __attribute__((ext_vector_type(4)));

#if __has_builtin(__builtin_amdgcn_logf)
#define FAST_LOG2(x) __builtin_amdgcn_logf(x)
#else
#define FAST_LOG2(x) log2f(x)
#endif
#if __has_builtin(__builtin_amdgcn_exp2f)
#define FAST_EXP2(x) __builtin_amdgcn_exp2f(x)
#else
#define FAST_EXP2(x) exp2f(x)
#endif
#if __has_builtin(__builtin_amdgcn_rcpf)
#define FAST_RCP(x) __builtin_amdgcn_rcpf(x)
#else
#define FAST_RCP(x) (1.0f/(x))
#endif

static __device__ __forceinline__ int refl(int i, int n) {
    if (i < 0) i = -i;
    else if (i >= n) i = 2*n - 2 - i;
    return i;
}
static __device__ __forceinline__ float lum(float r, float g, float b) {
    return 0.2126f*r + 0.7152f*g + 0.0722f*b;
}
static __device__ __forceinline__ float lg(float y) {
    return FAST_LOG2(fmaxf(y, 1e-6f));
}
static __device__ __forceinline__ void nt_store4(float* p, float a, float b,
                                                 float c, float d) {
    f32x4 v; v.x = a; v.y = b; v.z = c; v.w = d;
    __builtin_nontemporal_store(v, (f32x4*)p);
}

// K1: luma + log2 + exact 2x2-average downsample. 2 outputs/thread, float4 loads.
__global__ __launch_bounds__(256) void k_down(const float* __restrict__ x,
                                              float* __restrict__ I) {
    int t = blockIdx.x * 256 + threadIdx.x;     // 0 .. 1,036,799
    int p = t * 2;
    int i = p / W_D;
    int j = p - i * W_D;                        // even
    const float4* r0 = (const float4*)(x + ((size_t)(2*i)   * W_FULL + 2*j) * 3);
    const float4* r1 = (const float4*)(x + ((size_t)(2*i+1) * W_FULL + 2*j) * 3);
    float4 a0 = r0[0], a1 = r0[1], a2 = r0[2];
    float4 b0 = r1[0], b1 = r1[1], b2 = r1[2];
    float y00 = lum(a0.x,a0.y,a0.z), y01 = lum(a0.w,a1.x,a1.y);
    float y02 = lum(a1.z,a1.w,a2.x), y03 = lum(a2.y,a2.z,a2.w);
    float y10 = lum(b0.x,b0.y,b0.z), y11 = lum(b0.w,b1.x,b1.y);
    float y12 = lum(b1.z,b1.w,b2.x), y13 = lum(b2.y,b2.z,b2.w);
    float o0 = 0.25f * (lg(y00)+lg(y01)+lg(y10)+lg(y11));
    float o1 = 0.25f * (lg(y02)+lg(y03)+lg(y12)+lg(y13));
    *(float2*)(I + (size_t)i * W_D + j) = make_float2(o0, o1);
}

// K2: fused guided filter + tone map (champion). Stages 1-5 compute the
// guided-filter base in LDS; phase B stages results in dead filter LDS and
// drains with DENSE nontemporal stores (full 64B lines per wave instruction).
__global__ __launch_bounds__(512, 6) void k_fused5(const float* __restrict__ I,
                                                   const float* __restrict__ x,
                                                   float* __restrict__ out) {
    __shared__ char lds[52088];
    float*  sIc   = (float*) (lds);             // 34x35 f   (4,760B)  live t2..t5
    float*  sIf   = (float*) (lds + 4760);      // 66x67 f   (17,688B) live t1..t2
    float2* ab    = (float2*)(lds + 4760);      // 50x51 f2  (20,400B) live t3..t4 (over sIf)
    float2* hI    = (float2*)(lds + 25160);     // 66x51 f2  (26,928B) live t2..t3
    float2* hab   = (float2*)(lds + 25160);     // 50x35 f2  (14,000B) live t4..t5 (over hI)
    float*  baseL = (float*) (lds + 39160);     // 34x35 f   (4,760B)  live t5..B
    float*  stage = (float*) (lds + 8192);      // 24,576B  phase-B staging (over dead ab/hI/hab)

    int tx0 = blockIdx.x * 32;          // base-tile col origin (downsampled coords)
    int ty0 = blockIdx.y * 32;          // base-tile row origin
    int tid = threadIdx.x;

    // stage 1: load 66x66 I halo (reflect), pitch 67
    for (int e = tid; e < 66 * 66; e += 512) {
        int r = e / 66, c = e - r * 66;
        sIf[r * 67 + c] =
            I[(size_t)refl(ty0 - 17 + r, H_D) * W_D + refl(tx0 - 17 + c, W_D)];
    }
    __syncthreads();

    // stage 2: horizontal 17-sums of (I, I*I): 66 rows x 50 cols, 5 runs of 10/row
    if (tid < 330) {
        int r = tid / 5, run = tid - (tid / 5) * 5;
        int c0 = run * 10;
        const float* p = &sIf[r * 67 + c0];
        float s1 = 0.f, s2 = 0.f;
        #pragma unroll
        for (int k = 0; k < KLEN; ++k) { float v = p[k]; s1 += v; s2 += v * v; }
        float2* o = &hI[r * 51 + c0];
        o[0] = make_float2(s1, s2);
        #pragma unroll
        for (int m = 1; m < 10; ++m) {
            float vo = p[m - 1], vi = p[m + 16];
            s1 += vi - vo;
            s2 += vi * vi - vo * vo;
            o[m] = make_float2(s1, s2);
        }
    }
    // concurrent: copy center I (34x34, rows/cols 16..49) into sIc (reads sIf only)
    for (int e = tid; e < 34 * 34; e += 512) {
        int r = e / 34, c = e - r * 34;
        sIc[r * 35 + c] = sIf[(r + 16) * 67 + (c + 16)];
    }
    __syncthreads();

    // stage 3: vertical 17-sums -> (a,b) on 50x50, 5 runs of 10 rows (writes over sIf)
    if (tid < 250) {
        int c = tid % 50, run = tid / 50;
        int r0 = run * 10;
        const float2* p = &hI[r0 * 51 + c];
        float s1 = 0.f, s2 = 0.f;
        #pragma unroll
        for (int k = 0; k < KLEN; ++k) { float2 v = p[k * 51]; s1 += v.x; s2 += v.y; }
        float2* o = &ab[r0 * 51 + c];
        #pragma unroll
        for (int m = 0; m < 10; ++m) {
            if (m) {
                float2 vi = p[(m + 16) * 51], vo = p[(m - 1) * 51];
                s1 += vi.x - vo.x;
                s2 += vi.y - vo.y;
            }
            float mI  = s1 * INV_K2;
            float mII = s2 * INV_K2;
            float var = mII - mI * mI;
            float av  = var / (var + 1e-3f);
            o[m * 51] = make_float2(av, mI - av * mI);
        }
    }
    __syncthreads();

    // stage 4: horizontal 17-sums of (a,b): 50 rows x 34 cols, runs 9/9/8/8 (over hI)
    if (tid < 200) {
        int r = tid % 50, run = tid / 50;
        int c0  = (run < 2) ? run * 9 : 18 + (run - 2) * 8;
        int len = (run < 2) ? 9 : 8;
        const float2* p = &ab[r * 51 + c0];
        float sa = 0.f, sb = 0.f;
        #pragma unroll
        for (int k = 0; k < KLEN; ++k) { float2 v = p[k]; sa += v.x; sb += v.y; }
        float2* o = &hab[r * 35 + c0];
        o[0] = make_float2(sa, sb);
        #pragma unroll
        for (int m = 1; m < 9; ++m) {
            if (m < len) {
                float2 vi = p[m + 16], vo = p[m - 1];
                sa += vi.x - vo.x;
                sb += vi.y - vo.y;
                o[m] = make_float2(sa, sb);
            }
        }
    }
    __syncthreads();

    // stage 5: vertical 17-sums -> baseL 34x34, runs 9/9/8/8 rows; combine with sIc
    if (tid < 136) {
        int cc = tid % 34, run = tid / 34;
        int r0  = (run < 2) ? run * 9 : 18 + (run - 2) * 8;
        int len = (run < 2) ? 9 : 8;
        const float2* p = &hab[r0 * 35 + cc];
        float sa = 0.f, sb = 0.f;
        #pragma unroll
        for (int k = 0; k < KLEN; ++k) { float2 v = p[k * 35]; sa += v.x; sb += v.y; }
        #pragma unroll
        for (int m = 0; m < 9; ++m) {
            if (m < len) {
                if (m) {
                    float2 vi = p[(m + 16) * 35], vo = p[(m - 1) * 35];
                    sa += vi.x - vo.x;
                    sb += vi.y - vo.y;
                }
                int br = r0 + m;
                baseL[br * 35 + cc] =
                    (sa * INV_K2) * sIc[br * 35 + cc] + sb * INV_K2;
            }
        }
    }
    __syncthreads();

    // phase B: tone-map 64x64 output region; per 32-row chunk: compute -> LDS
    // staging -> dense NT drain (each 64B line written whole by one wave instr).
    int q  = tid & 15;                  // col group
    int r  = tid >> 4;                  // 0..31
    int gc0 = tx0 + 2 * q - 1;
    int l0 = max(gc0, 0) - (tx0 - 1);
    int l1 = 2 * q + 1, l2 = 2 * q + 2;
    int l3 = min(gc0 + 3, W_D - 1) - (tx0 - 1);
    int j0 = tx0 * 2 + q * 4;

    #pragma unroll
    for (int s = 0; s < 2; ++s) {
        int oy = ty0 * 2 + r + s * 32;
        if (oy < H_FULL) {
            int y0g = (oy - 1) >> 1;
            int ly0 = max(y0g, 0) - (ty0 - 1);
            int ly1 = min(y0g + 1, H_D - 1) - (ty0 - 1);
            float wy = (oy & 1) ? 0.25f : 0.75f;
            const float* b0r = &baseL[ly0 * 35];
            const float* b1r = &baseL[ly1 * 35];
            float v0 = b0r[l0] + (b1r[l0] - b0r[l0]) * wy;
            float v1 = b0r[l1] + (b1r[l1] - b0r[l1]) * wy;
            float v2 = b0r[l2] + (b1r[l2] - b0r[l2]) * wy;
            float v3 = b0r[l3] + (b1r[l3] - b0r[l3]) * wy;
            float Yb[4];
            Yb[0] = v0 + (v1 - v0) * 0.75f;
            Yb[1] = v1 + (v2 - v1) * 0.25f;
            Yb[2] = v1 + (v2 - v1) * 0.75f;
            Yb[3] = v2 + (v3 - v2) * 0.25f;

            size_t off = ((size_t)oy * W_FULL + j0) * 3;
            const float4* px = (const float4*)(x + off);
            float4 q0 = px[0], q1 = px[1], q2 = px[2];
            float rgb[12] = {q0.x,q0.y,q0.z,q0.w, q1.x,q1.y,q1.z,q1.w, q2.x,q2.y,q2.z,q2.w};
            float res[12];
            #pragma unroll
            for (int k = 0; k < 4; ++k) {
                float rr = rgb[3*k], gg = rgb[3*k+1], bb = rgb[3*k+2];
                float Y = lum(rr, gg, bb);
                float sc = fmaxf(Y, 1e-6f) * FAST_EXP2(-0.3f * Yb[k]) * FAST_RCP(Y + 1e-4f);
                res[3*k]   = fminf(fmaxf(rr * sc, 0.f), 1.f);
                res[3*k+1] = fminf(fmaxf(gg * sc, 0.f), 1.f);
                res[3*k+2] = fminf(fmaxf(bb * sc, 0.f), 1.f);
            }
            // stage into LDS at pixel position: row r (0..31), col-group q (48B)
            float* st = stage + r * 192 + q * 12;
            *(float4*)(st)     = make_float4(res[0], res[1], res[2],  res[3]);
            *(float4*)(st + 4) = make_float4(res[4], res[5], res[6],  res[7]);
            *(float4*)(st + 8) = make_float4(res[8], res[9], res[10], res[11]);
        }
        __syncthreads();

        // dense drain: 1536 float4s (32 rows x 768B), 3 per thread, NT stores
        int rowbase = ty0 * 2 + s * 32;
        #pragma unroll
        for (int k = 0; k < 3; ++k) {
            int f4 = tid + k * 512;
            int rr = f4 / 48, cc = f4 - rr * 48;
            if (rowbase + rr < H_FULL) {
                float4 v = *((float4*)stage + f4);
                float* po = out + ((size_t)(rowbase + rr) * W_FULL + tx0 * 2) * 3 + cc * 4;
                nt_store4(po, v.x, v.y, v.z, v.w);
            }
        }
        if (s == 0) __syncthreads();    // protect stage before chunk-1 overwrite
    }
}

extern "C" void kernel_launch(void* const* d_in, const int* in_sizes, int n_in,
                              void* d_out, int out_size, void* d_ws, size_t ws_size,
                              hipStream_t stream) {
    (void)in_sizes; (void)n_in; (void)out_size; (void)ws_size;
    const float* x = (const float*)d_in[0];
    float* out = (float*)d_out;
    float* I = (float*)d_ws;      // Y_log_down, 8.3 MB, rewritten every call

    k_down  <<<dim3(4050, 1, 1), dim3(256, 1, 1), 0, stream>>>(x, I);
    k_fused5<<<dim3(60, 34, 1),  dim3(512, 1, 1), 0, stream>>>(I, x, out);
}